// Round 5
// baseline (163.698 us; speedup 1.0000x reference)
//
#include <hip/hip_runtime.h>
#include <hip/hip_bf16.h>

// DotProductAttention: B=16, LQ=LKV=2048, D=64, fp32 in/out, per-batch valid_lens.
// Flash-style online softmax; hi/lo bf16 split MFMA (near-fp32 accuracy).
// R3: swapped QK^T (mfma(K,Q)) -> in-register softmax, P feeds PV directly;
//     V store-side permuted so PV read side matches P's register key order.
// R4: + s_setprio(1) around MFMA clusters (T5; 2 blocks/CU give wave role
//     diversity for the CU scheduler to arbitrate). No structural changes.

#define NB   16
#define LQS  2048
#define LKVS 2048
#define DH   64
#define QBLK 64
#define KVB  64

typedef short bf16x8 __attribute__((ext_vector_type(8)));
typedef float f32x4  __attribute__((ext_vector_type(4)));

__device__ __forceinline__ unsigned short f2bf(float x) {
    return __builtin_bit_cast(unsigned short, __float2bfloat16(x));
}
__device__ __forceinline__ float bf2f(unsigned short h) {
    return __uint_as_float(((unsigned int)h) << 16);
}

__global__ __launch_bounds__(256, 2) void attn_fa(
    const float* __restrict__ Qg, const float* __restrict__ Kg,
    const float* __restrict__ Vg, const int* __restrict__ vlg,
    float* __restrict__ Og)
{
    // K: [key][d] bf16 rows, XOR-swizzled (^ (key&7)<<3 at 8-ushort granularity).
    // V: transposed [d][pos(key)] with pos(t)=(t&~31)|(((t>>2)&3)<<3)|(((t>>4)&1)<<2)
    //    so that PV's canonical b128 read at position 32s+8g+i yields key
    //    32s+4g+(i&3)+16(i>>2) == the key held in P's register (g,i). Same XOR swizzle.
    __shared__ __align__(16) unsigned short sKhi[KVB * DH];
    __shared__ __align__(16) unsigned short sKlo[KVB * DH];
    __shared__ __align__(16) unsigned short sVhi[DH * KVB];
    __shared__ __align__(16) unsigned short sVlo[DH * KVB];

    const int b    = blockIdx.y;
    const int q0   = blockIdx.x * QBLK;
    const int tid  = threadIdx.x;
    const int w    = tid >> 6;
    const int lane = tid & 63;
    const int lr   = lane & 15;   // q column (QK^T out / PV A row / o col=d offset base)
    const int lg   = lane >> 4;   // 0..3 k-group
    const int n_valid = vlg[b];

    // ---- Q fragments (B-operand; col = q = lr): scale by 1/8 (exact) then split ----
    bf16x8 qhi[2], qlo[2];
    {
        const float* qp = Qg + ((size_t)b * LQS + q0 + w * 16 + lr) * DH;
        #pragma unroll
        for (int s = 0; s < 2; ++s) {
            const float4 a = *(const float4*)(qp + s * 32 + lg * 8);
            const float4 c = *(const float4*)(qp + s * 32 + lg * 8 + 4);
            const float vv[8] = {a.x, a.y, a.z, a.w, c.x, c.y, c.z, c.w};
            #pragma unroll
            for (int i = 0; i < 8; ++i) {
                const float x = vv[i] * 0.125f;
                const unsigned short h = f2bf(x);
                qhi[s][i] = (short)h;
                qlo[s][i] = (short)f2bf(x - bf2f(h));
            }
        }
    }

    f32x4 o[4];
    #pragma unroll
    for (int nt = 0; nt < 4; ++nt) { o[nt][0]=0.f; o[nt][1]=0.f; o[nt][2]=0.f; o[nt][3]=0.f; }
    float m_q = -__builtin_inff();   // running max for q = lr (replicated across lg)
    float l_q = 0.f;                 // running denom for q = lr

    const int nsteps = (n_valid + KVB - 1) / KVB;
    for (int st = 0; st < nsteps; ++st) {
        const int kv0 = st * KVB;
        __syncthreads();   // previous tile fully consumed before overwrite
        {
            const float* kp = Kg + ((size_t)b * LKVS + kv0) * DH;
            const float* vp = Vg + ((size_t)b * LKVS + kv0) * DH;
            // ---- K: [key][d] rows, swizzled ushort4 stores ----
            #pragma unroll
            for (int it = 0; it < 4; ++it) {
                const int idx = tid + it * 256;          // 1024 float4-chunks
                const int key = idx >> 4, f4 = idx & 15;
                const float4 kq = *(const float4*)(kp + key * DH + f4 * 4);
                const float ka[4] = {kq.x, kq.y, kq.z, kq.w};
                unsigned short kh[4], kl[4];
                #pragma unroll
                for (int i = 0; i < 4; ++i) {
                    kh[i] = f2bf(ka[i]);
                    kl[i] = f2bf(ka[i] - bf2f(kh[i]));
                }
                const int kb_ = key * 64 + (((f4 * 4) & ~7) ^ ((key & 7) << 3)) + (f4 & 1) * 4;
                *(ushort4*)(&sKhi[kb_]) = make_ushort4(kh[0], kh[1], kh[2], kh[3]);
                *(ushort4*)(&sKlo[kb_]) = make_ushort4(kl[0], kl[1], kl[2], kl[3]);
            }
            // ---- V: 4-key x 4-d register transpose; store at permuted position ----
            {
                const int kb = (tid >> 4) * 4;   // key base (0..60), 4-aligned
                const int db = (tid & 15) * 4;   // d base   (0..60)
                const int pb = (kb & ~31) | (((kb >> 2) & 3) << 3) | (((kb >> 4) & 1) << 2);
                const float4 vr0 = *(const float4*)(vp + (kb + 0) * DH + db);
                const float4 vr1 = *(const float4*)(vp + (kb + 1) * DH + db);
                const float4 vr2 = *(const float4*)(vp + (kb + 2) * DH + db);
                const float4 vr3 = *(const float4*)(vp + (kb + 3) * DH + db);
                #pragma unroll
                for (int i = 0; i < 4; ++i) {
                    const int d = db + i;
                    const float f0 = (&vr0.x)[i], f1 = (&vr1.x)[i];
                    const float f2_ = (&vr2.x)[i], f3 = (&vr3.x)[i];
                    const unsigned short h0 = f2bf(f0), h1 = f2bf(f1);
                    const unsigned short h2 = f2bf(f2_), h3 = f2bf(f3);
                    const int vi = d * 64 + (pb ^ ((d & 7) << 3));
                    *(ushort4*)(&sVhi[vi]) = make_ushort4(h0, h1, h2, h3);
                    *(ushort4*)(&sVlo[vi]) = make_ushort4(
                        f2bf(f0 - bf2f(h0)), f2bf(f1 - bf2f(h1)),
                        f2bf(f2_ - bf2f(h2)), f2bf(f3 - bf2f(h3)));
                }
            }
        }
        __syncthreads();

        // ---- QK^T swapped: P[key, q] = mfma(K, Q).  A=K row = key = kt*16+lr,
        //      D: col=lane&15=q, row=key=16*kt+4*lg+r  ->  p_[kt][r] ----
        float p_[4][4];
        __builtin_amdgcn_s_setprio(1);
        #pragma unroll
        for (int kt = 0; kt < 4; ++kt) {
            f32x4 acc = {0.f, 0.f, 0.f, 0.f};
            const int key = kt * 16 + lr;
            #pragma unroll
            for (int s = 0; s < 2; ++s) {
                const int ki = key * 64 + ((s * 32 + lg * 8) ^ ((key & 7) << 3));
                const bf16x8 khi = *(const bf16x8*)(&sKhi[ki]);
                const bf16x8 klo = *(const bf16x8*)(&sKlo[ki]);
                acc = __builtin_amdgcn_mfma_f32_16x16x32_bf16(khi, qhi[s], acc, 0, 0, 0);
                acc = __builtin_amdgcn_mfma_f32_16x16x32_bf16(khi, qlo[s], acc, 0, 0, 0);
                acc = __builtin_amdgcn_mfma_f32_16x16x32_bf16(klo, qhi[s], acc, 0, 0, 0);
            }
            #pragma unroll
            for (int r = 0; r < 4; ++r) p_[kt][r] = acc[r];
        }
        __builtin_amdgcn_s_setprio(0);

        // ---- mask (partial last tile only): key = kv0 + 16*kt + 4*lg + r ----
        if (kv0 + KVB > n_valid) {
            #pragma unroll
            for (int kt = 0; kt < 4; ++kt) {
                #pragma unroll
                for (int r = 0; r < 4; ++r) {
                    if (kv0 + kt * 16 + lg * 4 + r >= n_valid) p_[kt][r] = -1000000.0f;
                }
            }
        }

        // ---- in-register online softmax for q = lr (16 regs + 2 shuffles) ----
        float tm = p_[0][0];
        #pragma unroll
        for (int kt = 0; kt < 4; ++kt) {
            #pragma unroll
            for (int r = 0; r < 4; ++r) tm = fmaxf(tm, p_[kt][r]);
        }
        tm = fmaxf(tm, __shfl_xor(tm, 16));
        tm = fmaxf(tm, __shfl_xor(tm, 32));
        const float mn = fmaxf(m_q, tm);
        const float sc = __expf(m_q - mn);    // first tile: exp(-inf) = 0
        float rs = 0.f;
        #pragma unroll
        for (int kt = 0; kt < 4; ++kt) {
            #pragma unroll
            for (int r = 0; r < 4; ++r) {
                p_[kt][r] = __expf(p_[kt][r] - mn);
                rs += p_[kt][r];
            }
        }
        rs += __shfl_xor(rs, 16);
        rs += __shfl_xor(rs, 32);
        l_q = l_q * sc + rs;
        m_q = mn;
        // o rows are q = 4*lg + r; sc lives at lane q -> broadcast
        #pragma unroll
        for (int r = 0; r < 4; ++r) {
            const float scr = __shfl(sc, lg * 4 + r);
            #pragma unroll
            for (int nt = 0; nt < 4; ++nt) o[nt][r] *= scr;
        }

        // ---- PV: O += P * V; P direct from regs (A pos (lg,i) = key 32s+4lg+(i&3)+16(i>>2)) ----
        #pragma unroll
        for (int s = 0; s < 2; ++s) {
            bf16x8 phi, plo;
            #pragma unroll
            for (int i = 0; i < 8; ++i) {
                const float v = p_[2 * s + (i >> 2)][i & 3];
                const unsigned short h = f2bf(v);
                phi[i] = (short)h;
                plo[i] = (short)f2bf(v - bf2f(h));
            }
            const int cb = s * 32 + lg * 8;
            __builtin_amdgcn_s_setprio(1);
            #pragma unroll
            for (int nt = 0; nt < 4; ++nt) {
                const int d  = nt * 16 + lr;
                const int vi = d * 64 + (cb ^ ((d & 7) << 3));
                const bf16x8 vhi = *(const bf16x8*)(&sVhi[vi]);
                const bf16x8 vlo = *(const bf16x8*)(&sVlo[vi]);
                o[nt] = __builtin_amdgcn_mfma_f32_16x16x32_bf16(phi, vhi, o[nt], 0, 0, 0);
                o[nt] = __builtin_amdgcn_mfma_f32_16x16x32_bf16(plo, vhi, o[nt], 0, 0, 0);
                o[nt] = __builtin_amdgcn_mfma_f32_16x16x32_bf16(phi, vlo, o[nt], 0, 0, 0);
            }
            __builtin_amdgcn_s_setprio(0);
        }
    }

    // ---- epilogue: O / l  (l lives at lane q; o rows are q = 4*lg + r) ----
    const float inv = 1.0f / l_q;   // n_valid >= 1 => l > 0
    #pragma unroll
    for (int r = 0; r < 4; ++r) {
        const float invr = __shfl(inv, lg * 4 + r);
        const int row = lg * 4 + r;
        float* op = Og + ((size_t)b * LQS + q0 + w * 16 + row) * DH + lr;
        #pragma unroll
        for (int nt = 0; nt < 4; ++nt) op[nt * 16] = o[nt][r] * invr;
    }
}

extern "C" void kernel_launch(void* const* d_in, const int* in_sizes, int n_in,
                              void* d_out, int out_size, void* d_ws, size_t ws_size,
                              hipStream_t stream) {
    (void)in_sizes; (void)n_in; (void)out_size; (void)d_ws; (void)ws_size;
    const float* Q  = (const float*)d_in[0];
    const float* K  = (const float*)d_in[1];
    const float* V  = (const float*)d_in[2];
    const int*   vl = (const int*)d_in[3];
    float* O = (float*)d_out;
    dim3 grid(LQS / QBLK, NB);
    attn_fa<<<grid, 256, 0, stream>>>(Q, K, V, vl, O);
}

// Round 6
// 129.281 us; speedup vs baseline: 1.2662x; 1.2662x over previous
//
#include <hip/hip_runtime.h>
#include <hip/hip_bf16.h>

// DotProductAttention: B=16, LQ=LKV=2048, D=64, fp32 in/out, per-batch valid_lens.
// Flash-style online softmax; hi/lo bf16 split MFMA (near-fp32 accuracy).
// R3: swapped QK^T (mfma(K,Q)) -> in-register softmax, P feeds PV directly.
// R4: + s_setprio(1) around MFMA clusters (T5).
// R5 (counter-driven: Occupancy 13%, MfmaUtil 8%, VALU 15% -> latency/imbalance
//     bound): in-block KV-split. 512-thread blocks = 2 wave-groups of 4 waves;
//     group g handles tiles st = 2*jt+g in its own 32KB LDS set (64KB total,
//     2 blocks/CU -> 16 waves/CU = 2x occupancy), flash-combine at the end.

#define NB   16
#define LQS  2048
#define LKVS 2048
#define DH   64
#define QBLK 64
#define KVB  64

typedef short bf16x8 __attribute__((ext_vector_type(8)));
typedef float f32x4  __attribute__((ext_vector_type(4)));

__device__ __forceinline__ unsigned short f2bf(float x) {
    return __builtin_bit_cast(unsigned short, __float2bfloat16(x));
}
__device__ __forceinline__ float bf2f(unsigned short h) {
    return __uint_as_float(((unsigned int)h) << 16);
}

__global__ __launch_bounds__(512, 4) void attn_fa(
    const float* __restrict__ Qg, const float* __restrict__ Kg,
    const float* __restrict__ Vg, const int* __restrict__ vlg,
    float* __restrict__ Og)
{
    // Per group: K [key][d] bf16 rows XOR-swizzled; V transposed [d][pos(key)]
    // with pos(t)=(t&~31)|(((t>>2)&3)<<3)|(((t>>4)&1)<<2) so PV's b128 read at
    // position 32s+8g+i yields the key held in P's register (g,i).
    __shared__ __align__(16) unsigned short sMem[2][4 * KVB * DH];   // 64 KB

    const int b    = blockIdx.y;
    const int q0   = blockIdx.x * QBLK;
    const int tid  = threadIdx.x;
    const int wg   = tid >> 8;        // KV-split group 0/1
    const int gtid = tid & 255;       // thread id within group
    const int w4   = (tid >> 6) & 3;  // wave within group
    const int lane = tid & 63;
    const int lr   = lane & 15;       // q column
    const int lg   = lane >> 4;       // k-group 0..3
    const int n_valid = vlg[b];

    unsigned short* sKhi = &sMem[wg][0];
    unsigned short* sKlo = &sMem[wg][4096];
    unsigned short* sVhi = &sMem[wg][8192];
    unsigned short* sVlo = &sMem[wg][12288];

    // ---- Q fragments (B-operand; col = q = lr): scale by 1/8 (exact) then split ----
    bf16x8 qhi[2], qlo[2];
    {
        const float* qp = Qg + ((size_t)b * LQS + q0 + w4 * 16 + lr) * DH;
        #pragma unroll
        for (int s = 0; s < 2; ++s) {
            const float4 a = *(const float4*)(qp + s * 32 + lg * 8);
            const float4 c = *(const float4*)(qp + s * 32 + lg * 8 + 4);
            const float vv[8] = {a.x, a.y, a.z, a.w, c.x, c.y, c.z, c.w};
            #pragma unroll
            for (int i = 0; i < 8; ++i) {
                const float x = vv[i] * 0.125f;
                const unsigned short h = f2bf(x);
                qhi[s][i] = (short)h;
                qlo[s][i] = (short)f2bf(x - bf2f(h));
            }
        }
    }

    f32x4 o[4];
    #pragma unroll
    for (int nt = 0; nt < 4; ++nt) { o[nt][0]=0.f; o[nt][1]=0.f; o[nt][2]=0.f; o[nt][3]=0.f; }
    float m_q = -__builtin_inff();
    float l_q = 0.f;

    const int nsteps = (n_valid + KVB - 1) / KVB;
    const int rounds = (nsteps + 1) >> 1;
    for (int jt = 0; jt < rounds; ++jt) {
        const int st  = 2 * jt + wg;
        const bool act = (st < nsteps);
        const int kv0 = st * KVB;
        __syncthreads();   // own buffer fully consumed (block-uniform barrier)
        if (act) {
            const float* kp = Kg + ((size_t)b * LKVS + kv0) * DH;
            const float* vp = Vg + ((size_t)b * LKVS + kv0) * DH;
            // ---- K: [key][d] rows, swizzled ushort4 stores ----
            #pragma unroll
            for (int it = 0; it < 4; ++it) {
                const int idx = gtid + it * 256;          // 1024 float4-chunks
                const int key = idx >> 4, f4 = idx & 15;
                const float4 kq = *(const float4*)(kp + key * DH + f4 * 4);
                const float ka[4] = {kq.x, kq.y, kq.z, kq.w};
                unsigned short kh[4], kl[4];
                #pragma unroll
                for (int i = 0; i < 4; ++i) {
                    kh[i] = f2bf(ka[i]);
                    kl[i] = f2bf(ka[i] - bf2f(kh[i]));
                }
                const int kb_ = key * 64 + (((f4 * 4) & ~7) ^ ((key & 7) << 3)) + (f4 & 1) * 4;
                *(ushort4*)(&sKhi[kb_]) = make_ushort4(kh[0], kh[1], kh[2], kh[3]);
                *(ushort4*)(&sKlo[kb_]) = make_ushort4(kl[0], kl[1], kl[2], kl[3]);
            }
            // ---- V: 4-key x 4-d register transpose; store at permuted position ----
            {
                const int kb = (gtid >> 4) * 4;   // key base, 4-aligned
                const int db = (gtid & 15) * 4;   // d base
                const int pb = (kb & ~31) | (((kb >> 2) & 3) << 3) | (((kb >> 4) & 1) << 2);
                const float4 vr0 = *(const float4*)(vp + (kb + 0) * DH + db);
                const float4 vr1 = *(const float4*)(vp + (kb + 1) * DH + db);
                const float4 vr2 = *(const float4*)(vp + (kb + 2) * DH + db);
                const float4 vr3 = *(const float4*)(vp + (kb + 3) * DH + db);
                #pragma unroll
                for (int i = 0; i < 4; ++i) {
                    const int d = db + i;
                    const float f0 = (&vr0.x)[i], f1 = (&vr1.x)[i];
                    const float f2_ = (&vr2.x)[i], f3 = (&vr3.x)[i];
                    const unsigned short h0 = f2bf(f0), h1 = f2bf(f1);
                    const unsigned short h2 = f2bf(f2_), h3 = f2bf(f3);
                    const int vi = d * 64 + (pb ^ ((d & 7) << 3));
                    *(ushort4*)(&sVhi[vi]) = make_ushort4(h0, h1, h2, h3);
                    *(ushort4*)(&sVlo[vi]) = make_ushort4(
                        f2bf(f0 - bf2f(h0)), f2bf(f1 - bf2f(h1)),
                        f2bf(f2_ - bf2f(h2)), f2bf(f3 - bf2f(h3)));
                }
            }
        }
        __syncthreads();
        if (act) {
            // ---- QK^T swapped: P[key, q] = mfma(K, Q) ----
            float p_[4][4];
            __builtin_amdgcn_s_setprio(1);
            #pragma unroll
            for (int kt = 0; kt < 4; ++kt) {
                f32x4 acc = {0.f, 0.f, 0.f, 0.f};
                const int key = kt * 16 + lr;
                #pragma unroll
                for (int s = 0; s < 2; ++s) {
                    const int ki = key * 64 + ((s * 32 + lg * 8) ^ ((key & 7) << 3));
                    const bf16x8 khi = *(const bf16x8*)(&sKhi[ki]);
                    const bf16x8 klo = *(const bf16x8*)(&sKlo[ki]);
                    acc = __builtin_amdgcn_mfma_f32_16x16x32_bf16(khi, qhi[s], acc, 0, 0, 0);
                    acc = __builtin_amdgcn_mfma_f32_16x16x32_bf16(khi, qlo[s], acc, 0, 0, 0);
                    acc = __builtin_amdgcn_mfma_f32_16x16x32_bf16(klo, qhi[s], acc, 0, 0, 0);
                }
                #pragma unroll
                for (int r = 0; r < 4; ++r) p_[kt][r] = acc[r];
            }
            __builtin_amdgcn_s_setprio(0);

            // ---- mask (partial last tile): key = kv0 + 16*kt + 4*lg + r ----
            if (kv0 + KVB > n_valid) {
                #pragma unroll
                for (int kt = 0; kt < 4; ++kt) {
                    #pragma unroll
                    for (int r = 0; r < 4; ++r) {
                        if (kv0 + kt * 16 + lg * 4 + r >= n_valid) p_[kt][r] = -1000000.0f;
                    }
                }
            }

            // ---- in-register online softmax for q = lr ----
            float tm = p_[0][0];
            #pragma unroll
            for (int kt = 0; kt < 4; ++kt) {
                #pragma unroll
                for (int r = 0; r < 4; ++r) tm = fmaxf(tm, p_[kt][r]);
            }
            tm = fmaxf(tm, __shfl_xor(tm, 16));
            tm = fmaxf(tm, __shfl_xor(tm, 32));
            const float mn = fmaxf(m_q, tm);
            const float sc = __expf(m_q - mn);
            float rs = 0.f;
            #pragma unroll
            for (int kt = 0; kt < 4; ++kt) {
                #pragma unroll
                for (int r = 0; r < 4; ++r) {
                    p_[kt][r] = __expf(p_[kt][r] - mn);
                    rs += p_[kt][r];
                }
            }
            rs += __shfl_xor(rs, 16);
            rs += __shfl_xor(rs, 32);
            l_q = l_q * sc + rs;
            m_q = mn;
            #pragma unroll
            for (int r = 0; r < 4; ++r) {
                const float scr = __shfl(sc, lg * 4 + r);
                #pragma unroll
                for (int nt = 0; nt < 4; ++nt) o[nt][r] *= scr;
            }

            // ---- PV: O += P * V; P direct from regs ----
            #pragma unroll
            for (int s = 0; s < 2; ++s) {
                bf16x8 phi, plo;
                #pragma unroll
                for (int i = 0; i < 8; ++i) {
                    const float v = p_[2 * s + (i >> 2)][i & 3];
                    const unsigned short h = f2bf(v);
                    phi[i] = (short)h;
                    plo[i] = (short)f2bf(v - bf2f(h));
                }
                const int cb = s * 32 + lg * 8;
                __builtin_amdgcn_s_setprio(1);
                #pragma unroll
                for (int nt = 0; nt < 4; ++nt) {
                    const int d  = nt * 16 + lr;
                    const int vi = d * 64 + (cb ^ ((d & 7) << 3));
                    const bf16x8 vhi = *(const bf16x8*)(&sVhi[vi]);
                    const bf16x8 vlo = *(const bf16x8*)(&sVlo[vi]);
                    o[nt] = __builtin_amdgcn_mfma_f32_16x16x32_bf16(phi, vhi, o[nt], 0, 0, 0);
                    o[nt] = __builtin_amdgcn_mfma_f32_16x16x32_bf16(plo, vhi, o[nt], 0, 0, 0);
                    o[nt] = __builtin_amdgcn_mfma_f32_16x16x32_bf16(phi, vlo, o[nt], 0, 0, 0);
                }
                __builtin_amdgcn_s_setprio(0);
            }
        }
    }

    // ---- cross-group flash combine (reuse sMem[0] as fp32 scratch) ----
    __syncthreads();                       // all compute done; buffers dead
    float* fo = (float*)&sMem[0][0];       // 4096 floats O1 + 64 m1 + 64 l1
    if (wg == 1) {
        #pragma unroll
        for (int nt = 0; nt < 4; ++nt) {
            #pragma unroll
            for (int r = 0; r < 4; ++r)
                fo[(nt * 4 + r) * 256 + w4 * 64 + lane] = o[nt][r];
        }
        if (lg == 0) {
            fo[4096 + w4 * 16 + lr] = m_q;
            fo[4160 + w4 * 16 + lr] = l_q;
        }
    }
    __syncthreads();
    if (wg == 0) {
        const float m1 = fo[4096 + w4 * 16 + lr];
        const float l1 = fo[4160 + w4 * 16 + lr];
        const float mm = fmaxf(m_q, m1);
        const float a0 = __expf(m_q - mm);     // m_q finite (tile 0, key 0 valid)
        const float a1 = __expf(m1 - mm);      // m1 = -inf (idle group) -> 0
        const float inv = 1.0f / (a0 * l_q + a1 * l1);
        #pragma unroll
        for (int r = 0; r < 4; ++r) {
            const float a0r  = __shfl(a0, lg * 4 + r);
            const float a1r  = __shfl(a1, lg * 4 + r);
            const float invr = __shfl(inv, lg * 4 + r);
            const int row = lg * 4 + r;
            float* op = Og + ((size_t)b * LQS + q0 + w4 * 16 + row) * DH + lr;
            #pragma unroll
            for (int nt = 0; nt < 4; ++nt) {
                const float o1 = fo[(nt * 4 + r) * 256 + w4 * 64 + lane];
                op[nt * 16] = (a0r * o[nt][r] + a1r * o1) * invr;
            }
        }
    }
}

extern "C" void kernel_launch(void* const* d_in, const int* in_sizes, int n_in,
                              void* d_out, int out_size, void* d_ws, size_t ws_size,
                              hipStream_t stream) {
    (void)in_sizes; (void)n_in; (void)out_size; (void)d_ws; (void)ws_size;
    const float* Q  = (const float*)d_in[0];
    const float* K  = (const float*)d_in[1];
    const float* V  = (const float*)d_in[2];
    const int*   vl = (const int*)d_in[3];
    float* O = (float*)d_out;
    dim3 grid(LQS / QBLK, NB);
    attn_fa<<<grid, 512, 0, stream>>>(Q, K, V, vl, O);
}

// Round 7
// 119.557 us; speedup vs baseline: 1.3692x; 1.0813x over previous
//
#include <hip/hip_runtime.h>
#include <hip/hip_bf16.h>

// DotProductAttention: B=16, LQ=LKV=2048, D=64, fp32 in/out, per-batch valid_lens.
// Flash-style online softmax; hi/lo bf16 split MFMA (near-fp32 accuracy).
// R3: swapped QK^T (mfma(K,Q)) -> in-register softmax, P feeds PV directly.
// R4: + s_setprio around MFMA clusters (T5).
// R5: in-block KV-split, 512 thr = 2 wave-groups, 64KB LDS, flash-combine. 114->67us.
// R6 (counters: MfmaUtil 14 / VALU 27 / Occ 26 / BANK_CONFLICT 7.2M):
//  (a) T14 prefetch: next tile's global loads issued into regs before compute,
//      converted->LDS next round (HBM latency hidden under MFMA+softmax).
//  (b) V swizzle enriched: VSWZ(d)=((d&7)^(d>>3))<<3 on store+read; V-store
//      bank conflict 8-way -> 2-way(free). Read still 2-way free; key order proven.

#define NB   16
#define LQS  2048
#define LKVS 2048
#define DH   64
#define QBLK 64
#define KVB  64

typedef short bf16x8 __attribute__((ext_vector_type(8)));
typedef float f32x4  __attribute__((ext_vector_type(4)));

__device__ __forceinline__ unsigned short f2bf(float x) {
    return __builtin_bit_cast(unsigned short, __float2bfloat16(x));
}
__device__ __forceinline__ float bf2f(unsigned short h) {
    return __uint_as_float(((unsigned int)h) << 16);
}
__device__ __forceinline__ int vswz(int d) {          // V-tile swizzle (bits 3..5)
    return (((d & 7) ^ (d >> 3)) << 3);
}

__global__ __launch_bounds__(512, 4) void attn_fa(
    const float* __restrict__ Qg, const float* __restrict__ Kg,
    const float* __restrict__ Vg, const int* __restrict__ vlg,
    float* __restrict__ Og)
{
    // Per group: K [key][d] bf16 rows, swizzle ^((key&7)<<3); V transposed
    // [d][pos(key)], pos(t)=(t&~31)|(((t>>2)&3)<<3)|(((t>>4)&1)<<2), swizzle vswz(d).
    __shared__ __align__(16) unsigned short sMem[2][4 * KVB * DH];   // 64 KB

    const int b    = blockIdx.y;
    const int q0   = blockIdx.x * QBLK;
    const int tid  = threadIdx.x;
    const int wg   = tid >> 8;        // KV-split group 0/1
    const int gtid = tid & 255;       // thread id within group
    const int w4   = (tid >> 6) & 3;  // wave within group
    const int lane = tid & 63;
    const int lr   = lane & 15;       // q column
    const int lg   = lane >> 4;       // k-group 0..3
    const int n_valid = vlg[b];

    unsigned short* sKhi = &sMem[wg][0];
    unsigned short* sKlo = &sMem[wg][4096];
    unsigned short* sVhi = &sMem[wg][8192];
    unsigned short* sVlo = &sMem[wg][12288];

    // staging geometry (constant per thread)
    const int kb = (gtid >> 4) * 4;   // V key base, 4-aligned
    const int db = (gtid & 15) * 4;   // V d base
    const int pb = (kb & ~31) | (((kb >> 2) & 3) << 3) | (((kb >> 4) & 1) << 2);

    // ---- Q fragments (B-operand; col = q = lr): scale by 1/8 (exact) then split ----
    bf16x8 qhi[2], qlo[2];
    {
        const float* qp = Qg + ((size_t)b * LQS + q0 + w4 * 16 + lr) * DH;
        #pragma unroll
        for (int s = 0; s < 2; ++s) {
            const float4 a = *(const float4*)(qp + s * 32 + lg * 8);
            const float4 c = *(const float4*)(qp + s * 32 + lg * 8 + 4);
            const float vv[8] = {a.x, a.y, a.z, a.w, c.x, c.y, c.z, c.w};
            #pragma unroll
            for (int i = 0; i < 8; ++i) {
                const float x = vv[i] * 0.125f;
                const unsigned short h = f2bf(x);
                qhi[s][i] = (short)h;
                qlo[s][i] = (short)f2bf(x - bf2f(h));
            }
        }
    }

    f32x4 o[4];
    #pragma unroll
    for (int nt = 0; nt < 4; ++nt) { o[nt][0]=0.f; o[nt][1]=0.f; o[nt][2]=0.f; o[nt][3]=0.f; }
    float m_q = -__builtin_inff();
    float l_q = 0.f;

    const int nsteps = (n_valid + KVB - 1) / KVB;
    const int rounds = (nsteps + 1) >> 1;

    // ---- T14 prefetch registers: current tile's raw K/V ----
    float4 kq[4], vr[4];
    if (wg < nsteps) {   // prologue: load tile st=wg
        const float* kp = Kg + ((size_t)b * LKVS + wg * KVB) * DH;
        const float* vp = Vg + ((size_t)b * LKVS + wg * KVB) * DH;
        #pragma unroll
        for (int it = 0; it < 4; ++it) {
            const int idx = gtid + it * 256;
            kq[it] = *(const float4*)(kp + (idx >> 4) * DH + (idx & 15) * 4);
        }
        #pragma unroll
        for (int j = 0; j < 4; ++j)
            vr[j] = *(const float4*)(vp + (kb + j) * DH + db);
    }

    for (int jt = 0; jt < rounds; ++jt) {
        const int st  = 2 * jt + wg;
        const bool act = (st < nsteps);
        const int kv0 = st * KVB;
        __syncthreads();   // own buffer fully consumed (block-uniform barrier)
        if (act) {
            // ---- convert prefetched regs -> LDS ----
            #pragma unroll
            for (int it = 0; it < 4; ++it) {
                const int idx = gtid + it * 256;
                const int key = idx >> 4, f4 = idx & 15;
                const float ka[4] = {kq[it].x, kq[it].y, kq[it].z, kq[it].w};
                unsigned short kh[4], kl[4];
                #pragma unroll
                for (int i = 0; i < 4; ++i) {
                    kh[i] = f2bf(ka[i]);
                    kl[i] = f2bf(ka[i] - bf2f(kh[i]));
                }
                const int kb_ = key * 64 + (((f4 * 4) & ~7) ^ ((key & 7) << 3)) + (f4 & 1) * 4;
                *(ushort4*)(&sKhi[kb_]) = make_ushort4(kh[0], kh[1], kh[2], kh[3]);
                *(ushort4*)(&sKlo[kb_]) = make_ushort4(kl[0], kl[1], kl[2], kl[3]);
            }
            #pragma unroll
            for (int i = 0; i < 4; ++i) {
                const int d = db + i;
                const float f0 = (&vr[0].x)[i], f1 = (&vr[1].x)[i];
                const float f2_ = (&vr[2].x)[i], f3 = (&vr[3].x)[i];
                const unsigned short h0 = f2bf(f0), h1 = f2bf(f1);
                const unsigned short h2 = f2bf(f2_), h3 = f2bf(f3);
                const int vi = d * 64 + (pb ^ vswz(d));
                *(ushort4*)(&sVhi[vi]) = make_ushort4(h0, h1, h2, h3);
                *(ushort4*)(&sVlo[vi]) = make_ushort4(
                    f2bf(f0 - bf2f(h0)), f2bf(f1 - bf2f(h1)),
                    f2bf(f2_ - bf2f(h2)), f2bf(f3 - bf2f(h3)));
            }
        }
        __syncthreads();

        // ---- issue next tile's loads (latency hides under compute below) ----
        {
            const int stn = st + 2;
            if (stn < nsteps) {
                const float* kp = Kg + ((size_t)b * LKVS + stn * KVB) * DH;
                const float* vp = Vg + ((size_t)b * LKVS + stn * KVB) * DH;
                #pragma unroll
                for (int it = 0; it < 4; ++it) {
                    const int idx = gtid + it * 256;
                    kq[it] = *(const float4*)(kp + (idx >> 4) * DH + (idx & 15) * 4);
                }
                #pragma unroll
                for (int j = 0; j < 4; ++j)
                    vr[j] = *(const float4*)(vp + (kb + j) * DH + db);
            }
        }

        if (act) {
            // ---- QK^T swapped: P[key, q] = mfma(K, Q) ----
            float p_[4][4];
            __builtin_amdgcn_s_setprio(1);
            #pragma unroll
            for (int kt = 0; kt < 4; ++kt) {
                f32x4 acc = {0.f, 0.f, 0.f, 0.f};
                const int key = kt * 16 + lr;
                #pragma unroll
                for (int s = 0; s < 2; ++s) {
                    const int ki = key * 64 + ((s * 32 + lg * 8) ^ ((key & 7) << 3));
                    const bf16x8 khi = *(const bf16x8*)(&sKhi[ki]);
                    const bf16x8 klo = *(const bf16x8*)(&sKlo[ki]);
                    acc = __builtin_amdgcn_mfma_f32_16x16x32_bf16(khi, qhi[s], acc, 0, 0, 0);
                    acc = __builtin_amdgcn_mfma_f32_16x16x32_bf16(khi, qlo[s], acc, 0, 0, 0);
                    acc = __builtin_amdgcn_mfma_f32_16x16x32_bf16(klo, qhi[s], acc, 0, 0, 0);
                }
                #pragma unroll
                for (int r = 0; r < 4; ++r) p_[kt][r] = acc[r];
            }
            __builtin_amdgcn_s_setprio(0);

            // ---- mask (partial last tile): key = kv0 + 16*kt + 4*lg + r ----
            if (kv0 + KVB > n_valid) {
                #pragma unroll
                for (int kt = 0; kt < 4; ++kt) {
                    #pragma unroll
                    for (int r = 0; r < 4; ++r) {
                        if (kv0 + kt * 16 + lg * 4 + r >= n_valid) p_[kt][r] = -1000000.0f;
                    }
                }
            }

            // ---- in-register online softmax for q = lr ----
            float tm = p_[0][0];
            #pragma unroll
            for (int kt = 0; kt < 4; ++kt) {
                #pragma unroll
                for (int r = 0; r < 4; ++r) tm = fmaxf(tm, p_[kt][r]);
            }
            tm = fmaxf(tm, __shfl_xor(tm, 16));
            tm = fmaxf(tm, __shfl_xor(tm, 32));
            const float mn = fmaxf(m_q, tm);
            const float sc = __expf(m_q - mn);
            float rs = 0.f;
            #pragma unroll
            for (int kt = 0; kt < 4; ++kt) {
                #pragma unroll
                for (int r = 0; r < 4; ++r) {
                    p_[kt][r] = __expf(p_[kt][r] - mn);
                    rs += p_[kt][r];
                }
            }
            rs += __shfl_xor(rs, 16);
            rs += __shfl_xor(rs, 32);
            l_q = l_q * sc + rs;
            m_q = mn;
            #pragma unroll
            for (int r = 0; r < 4; ++r) {
                const float scr = __shfl(sc, lg * 4 + r);
                #pragma unroll
                for (int nt = 0; nt < 4; ++nt) o[nt][r] *= scr;
            }

            // ---- PV: O += P * V; P direct from regs ----
            #pragma unroll
            for (int s = 0; s < 2; ++s) {
                bf16x8 phi, plo;
                #pragma unroll
                for (int i = 0; i < 8; ++i) {
                    const float v = p_[2 * s + (i >> 2)][i & 3];
                    const unsigned short h = f2bf(v);
                    phi[i] = (short)h;
                    plo[i] = (short)f2bf(v - bf2f(h));
                }
                const int cb = s * 32 + lg * 8;
                __builtin_amdgcn_s_setprio(1);
                #pragma unroll
                for (int nt = 0; nt < 4; ++nt) {
                    const int d  = nt * 16 + lr;
                    const int vi = d * 64 + (cb ^ vswz(d));
                    const bf16x8 vhi = *(const bf16x8*)(&sVhi[vi]);
                    const bf16x8 vlo = *(const bf16x8*)(&sVlo[vi]);
                    o[nt] = __builtin_amdgcn_mfma_f32_16x16x32_bf16(phi, vhi, o[nt], 0, 0, 0);
                    o[nt] = __builtin_amdgcn_mfma_f32_16x16x32_bf16(plo, vhi, o[nt], 0, 0, 0);
                    o[nt] = __builtin_amdgcn_mfma_f32_16x16x32_bf16(phi, vlo, o[nt], 0, 0, 0);
                }
                __builtin_amdgcn_s_setprio(0);
            }
        }
    }

    // ---- cross-group flash combine (reuse sMem[0] as fp32 scratch) ----
    __syncthreads();                       // all compute done; buffers dead
    float* fo = (float*)&sMem[0][0];       // 4096 floats O1 + 64 m1 + 64 l1
    if (wg == 1) {
        #pragma unroll
        for (int nt = 0; nt < 4; ++nt) {
            #pragma unroll
            for (int r = 0; r < 4; ++r)
                fo[(nt * 4 + r) * 256 + w4 * 64 + lane] = o[nt][r];
        }
        if (lg == 0) {
            fo[4096 + w4 * 16 + lr] = m_q;
            fo[4160 + w4 * 16 + lr] = l_q;
        }
    }
    __syncthreads();
    if (wg == 0) {
        const float m1 = fo[4096 + w4 * 16 + lr];
        const float l1 = fo[4160 + w4 * 16 + lr];
        const float mm = fmaxf(m_q, m1);
        const float a0 = __expf(m_q - mm);     // m_q finite (tile 0, key 0 valid)
        const float a1 = __expf(m1 - mm);      // m1 = -inf (idle group) -> 0
        const float inv = 1.0f / (a0 * l_q + a1 * l1);
        #pragma unroll
        for (int r = 0; r < 4; ++r) {
            const float a0r  = __shfl(a0, lg * 4 + r);
            const float a1r  = __shfl(a1, lg * 4 + r);
            const float invr = __shfl(inv, lg * 4 + r);
            const int row = lg * 4 + r;
            float* op = Og + ((size_t)b * LQS + q0 + w4 * 16 + row) * DH + lr;
            #pragma unroll
            for (int nt = 0; nt < 4; ++nt) {
                const float o1 = fo[(nt * 4 + r) * 256 + w4 * 64 + lane];
                op[nt * 16] = (a0r * o[nt][r] + a1r * o1) * invr;
            }
        }
    }
}

extern "C" void kernel_launch(void* const* d_in, const int* in_sizes, int n_in,
                              void* d_out, int out_size, void* d_ws, size_t ws_size,
                              hipStream_t stream) {
    (void)in_sizes; (void)n_in; (void)out_size; (void)d_ws; (void)ws_size;
    const float* Q  = (const float*)d_in[0];
    const float* K  = (const float*)d_in[1];
    const float* V  = (const float*)d_in[2];
    const int*   vl = (const int*)d_in[3];
    float* O = (float*)d_out;
    dim3 grid(LQS / QBLK, NB);
    attn_fa<<<grid, 512, 0, stream>>>(Q, K, V, vl, O);
}